// Round 6
// baseline (238.409 us; speedup 1.0000x reference)
//
#include <hip/hip_runtime.h>
#include <math.h>

#define N_NODES 100000
#define N_EDGES 1200000
#define N_GRAPHS 1000
#define HID 64
#define NBUCK 256
#define NPB   391
#define BCAP  8192           // fixed staging capacity per bucket (~50 sigma)
#define EDGE_CHUNK 2048
#define S3_BLOCKS ((N_EDGES + EDGE_CHUNK - 1) / EDGE_CHUNK)   // 586
#define Z1_BLOCKS 512
#define LOG2E 1.4426950408889634f
#define N_TILES (N_NODES / 16)      // 6250, exact
#define AGG_BLOCKS (N_NODES / 16)   // 6250, exact

typedef _Float16 half_t;
typedef __attribute__((ext_vector_type(4))) _Float16 half4;
typedef __attribute__((ext_vector_type(8))) _Float16 half8;
typedef __attribute__((ext_vector_type(4))) float floatx4;

// ---------------- k_film: climber FiLM + W-pack + bucket_fill zero -----------
// blocks [0,125): climber LN + FiLM coeffs, 8 graphs per block
// blocks 125,126: pack Wg2 / Wc1 into per-lane MFMA fragment order:
//   Wp[((w*64+l)*2+ko)*8+j] = (half)W[(ko*32+(l>>4)*8+j)*64 + (l&15) + 16*w]
// block 0 additionally zeroes bucket_fill.
__global__ __launch_bounds__(1024) void k_film(
        const float* __restrict__ climber,
        const float* __restrict__ ln_g, const float* __restrict__ ln_b,
        const float* __restrict__ W_c, const float* __restrict__ b_c,
        const float* __restrict__ Wf1, const float* __restrict__ bf1,
        const float* __restrict__ Wf2, const float* __restrict__ bf2,
        const float* __restrict__ Wg2, const float* __restrict__ Wc1,
        float* __restrict__ gb1, float* __restrict__ gb2,
        half_t* __restrict__ Wp1, half_t* __restrict__ Wp2,
        int* __restrict__ bucket_fill) {
    int bid = blockIdx.x;
    if (bid == 0 && threadIdx.x < NBUCK) bucket_fill[threadIdx.x] = 0;
    if (bid >= 125) {
        const float* Wsrc = (bid == 125) ? Wg2 : Wc1;
        half_t*      Wdst = (bid == 125) ? Wp1 : Wp2;
        for (int idx = threadIdx.x; idx < 4096; idx += 1024) {
            int jj = idx & 7;
            int ko = (idx >> 3) & 1;
            int l  = (idx >> 4) & 63;
            int w  = idx >> 10;
            int c  = l & 15;
            int gg = l >> 4;
            Wdst[idx] = (half_t)Wsrc[(ko*32 + gg*8 + jj)*64 + c + 16*w];
        }
        return;
    }
    __shared__ float cl[8][64];
    int sub = threadIdx.x >> 7;         // graph-subgroup 0..7
    int j   = threadIdx.x & 127;
    int g   = bid * 8 + sub;
    if (j < 64) {
        float v[6];
        float mu = 0.f;
        #pragma unroll
        for (int k = 0; k < 6; k++) { v[k] = climber[g*6+k]; mu += v[k]; }
        mu *= (1.f/6.f);
        float var = 0.f;
        #pragma unroll
        for (int k = 0; k < 6; k++) { float d = v[k]-mu; var += d*d; }
        var *= (1.f/6.f);
        float rs = rsqrtf(var + 1e-5f);
        float acc = b_c[j];
        #pragma unroll
        for (int k = 0; k < 6; k++) {
            float cn = (v[k]-mu)*rs*ln_g[k] + ln_b[k];
            acc += cn * W_c[k*64+j];
        }
        cl[sub][j] = fmaxf(acc, 0.f);
    }
    __syncthreads();
    float a1 = bf1[j], a2 = bf2[j];
    #pragma unroll 8
    for (int k = 0; k < 64; k++) {
        float ck = cl[sub][k];
        a1 += ck * Wf1[k*128+j];
        a2 += ck * Wf2[k*128+j];
    }
    gb1[g*128+j] = a1;
    gb2[g*128+j] = a2;
}

// ---------------- k_pre2: edge binning (blocks < S3)  ||  layer-1 MFMA -------
// 512-thread blocks for finer CU packing (z1 VGPR-heavy; 3 blocks/CU vs 1).
// bin: single edge-list read; src/dst/bucket retained in registers.
// staged entry: (local_dst << 17) | src   (src < 2^17, local_dst < 512)
// z1: h1 = film1(x@W_in+b_in); z = h1@Wg1 (row-major); es/ed
__global__ __launch_bounds__(512) void k_pre2(
        const int* __restrict__ ei, int* __restrict__ bucket_fill,
        int* __restrict__ staged,
        const float* __restrict__ x, const int* __restrict__ batch,
        const float* __restrict__ W_in, const float* __restrict__ b_in,
        const float* __restrict__ gb1, const float* __restrict__ W,
        const float* __restrict__ a_src, const float* __restrict__ a_dst,
        half_t* __restrict__ z, float* __restrict__ es, float* __restrict__ ed) {
    if (blockIdx.x < S3_BLOCKS) {
        // -------- bin role --------
        __shared__ int hist[NBUCK];
        __shared__ int cursor[NBUCK];
        for (int t = threadIdx.x; t < NBUCK; t += 512) hist[t] = 0;
        __syncthreads();
        int e0 = blockIdx.x * EDGE_CHUNK;
        int n  = min(EDGE_CHUNK, N_EDGES - e0);
        int srcs[4], ldsts[4], bks[4];
        #pragma unroll
        for (int j = 0; j < 4; j++) {
            int idx = threadIdx.x + j*512;
            bks[j] = -1;
            if (idx < n) {
                int e = e0 + idx;
                srcs[j] = ei[e];
                int dst = ei[N_EDGES + e];
                int b = dst / NPB;
                bks[j] = b;
                ldsts[j] = dst - b * NPB;
                atomicAdd(&hist[b], 1);
            }
        }
        __syncthreads();
        if (threadIdx.x < NBUCK) {
            int hv = hist[threadIdx.x];
            int start = threadIdx.x * BCAP;
            if (hv) start += atomicAdd(&bucket_fill[threadIdx.x], hv);
            cursor[threadIdx.x] = start;
        }
        __syncthreads();
        #pragma unroll
        for (int j = 0; j < 4; j++) {
            if (bks[j] >= 0) {
                int pos = atomicAdd(&cursor[bks[j]], 1);
                staged[pos] = (ldsts[j] << 17) | srcs[j];
            }
        }
        return;
    }
    // -------- z1 role --------
    __shared__ float Wi[384];                // W_in row-major 6x64
    __shared__ float bi[64];
    __shared__ __align__(16) half_t zl[8][1024];
    for (int idx = threadIdx.x; idx < 384; idx += 512) Wi[idx] = W_in[idx];
    if (threadIdx.x < 64) bi[threadIdx.x] = b_in[threadIdx.x];
    int wave = threadIdx.x >> 6;        // 0..7
    int l    = threadIdx.x & 63;
    int c    = l & 15;
    int g    = l >> 4;
    half8 Bf[2][4];
    #pragma unroll
    for (int ko = 0; ko < 2; ko++) {
        #pragma unroll
        for (int nt = 0; nt < 4; nt++) {
            half8 bvec;
            #pragma unroll
            for (int j = 0; j < 8; j++)
                bvec[j] = (half_t)W[(ko*32 + g*8 + j)*64 + c + 16*nt];
            Bf[ko][nt] = bvec;
        }
    }
    float as4[4], ad4[4];
    #pragma unroll
    for (int nt = 0; nt < 4; nt++) {
        as4[nt] = a_src[c + 16*nt] * LOG2E;
        ad4[nt] = a_dst[c + 16*nt] * LOG2E;
    }
    __syncthreads();
    int nWaves = Z1_BLOCKS * 8;
    int wid = (blockIdx.x - S3_BLOCKS) * 8 + wave;
    half_t* zw = zl[wave];
    const float4* x4p = (const float4*)x;
    for (int t = wid; t < N_TILES; t += nWaves) {
        int m0 = t * 16;
        int i = m0 + c;
        float4 xa = x4p[i*2];
        float4 xb = x4p[i*2 + 1];
        float xv[6] = {xa.x, xa.y, xa.z, xa.w, xb.x, xb.y};
        int bg_ = batch[i];
        half8 A[2];
        #pragma unroll
        for (int s = 0; s < 2; s++) {
            int bk = s*32 + g*8;
            float acc[8];
            #pragma unroll
            for (int j = 0; j < 8; j++) acc[j] = bi[bk + j];
            #pragma unroll
            for (int kk = 0; kk < 6; kk++) {
                float xk = xv[kk];
                float4 w0 = *(const float4*)&Wi[kk*64 + bk];
                float4 w1 = *(const float4*)&Wi[kk*64 + bk + 4];
                acc[0] += xk*w0.x; acc[1] += xk*w0.y;
                acc[2] += xk*w0.z; acc[3] += xk*w0.w;
                acc[4] += xk*w1.x; acc[5] += xk*w1.y;
                acc[6] += xk*w1.z; acc[7] += xk*w1.w;
            }
            const float4* gbv = (const float4*)(gb1 + bg_*128);
            float4 ga0 = gbv[bk/4],      ga1 = gbv[bk/4 + 1];
            float4 be0 = gbv[16 + bk/4], be1 = gbv[16 + bk/4 + 1];
            half8 hv;
            hv[0] = (half_t)(acc[0]*(1.f+ga0.x) + be0.x);
            hv[1] = (half_t)(acc[1]*(1.f+ga0.y) + be0.y);
            hv[2] = (half_t)(acc[2]*(1.f+ga0.z) + be0.z);
            hv[3] = (half_t)(acc[3]*(1.f+ga0.w) + be0.w);
            hv[4] = (half_t)(acc[4]*(1.f+ga1.x) + be1.x);
            hv[5] = (half_t)(acc[5]*(1.f+ga1.y) + be1.y);
            hv[6] = (half_t)(acc[6]*(1.f+ga1.z) + be1.z);
            hv[7] = (half_t)(acc[7]*(1.f+ga1.w) + be1.w);
            A[s] = hv;
        }
        floatx4 D[4];
        #pragma unroll
        for (int nt = 0; nt < 4; nt++) {
            floatx4 acc = {0.f, 0.f, 0.f, 0.f};
            acc = __builtin_amdgcn_mfma_f32_16x16x32_f16(A[0], Bf[0][nt], acc, 0, 0, 0);
            acc = __builtin_amdgcn_mfma_f32_16x16x32_f16(A[1], Bf[1][nt], acc, 0, 0, 0);
            D[nt] = acc;
        }
        #pragma unroll
        for (int r = 0; r < 4; r++) {
            float ps = D[0][r]*as4[0] + D[1][r]*as4[1] + D[2][r]*as4[2] + D[3][r]*as4[3];
            float pd = D[0][r]*ad4[0] + D[1][r]*ad4[1] + D[2][r]*ad4[2] + D[3][r]*ad4[3];
            #pragma unroll
            for (int off = 1; off < 16; off <<= 1) {
                ps += __shfl_xor(ps, off, 16);
                pd += __shfl_xor(pd, off, 16);
            }
            if (c == 0) {
                es[m0 + g*4 + r] = ps;
                ed[m0 + g*4 + r] = pd;
            }
        }
        #pragma unroll
        for (int nt = 0; nt < 4; nt++) {
            #pragma unroll
            for (int r = 0; r < 4; r++)
                zw[(g*4 + r)*64 + c + 16*nt] = (half_t)D[nt][r];
        }
        __asm__ __volatile__("s_waitcnt lgkmcnt(0)" ::: "memory");
        const half8* zr = (const half8*)zw;
        half8 v0 = zr[l*2];
        half8 v1 = zr[l*2 + 1];
        half8* zo = (half8*)(z + (size_t)m0 * 64);
        zo[l*2]     = v0;
        zo[l*2 + 1] = v1;
        __asm__ __volatile__("s_waitcnt lgkmcnt(0)" ::: "memory");
    }
}

// ---------------- k_bcsr: compact staged -> csr_src + rowptr (512 threads) ---
__global__ __launch_bounds__(512) void k_bcsr(
        const int* __restrict__ staged, const int* __restrict__ bucket_fill,
        int* __restrict__ rowptr, int* __restrict__ csr_src) {
    __shared__ int bb[NBUCK];       // inclusive scan of bucket_fill
    __shared__ int ldeg[NPB];
    __shared__ int sc[512];
    __shared__ int cursor[NPB];
    int b = blockIdx.x;
    if (threadIdx.x < NBUCK) bb[threadIdx.x] = bucket_fill[threadIdx.x];
    __syncthreads();
    for (int off = 1; off < NBUCK; off <<= 1) {
        int u = 0;
        if (threadIdx.x < NBUCK && threadIdx.x >= off) u = bb[threadIdx.x - off];
        __syncthreads();
        if (threadIdx.x < NBUCK) bb[threadIdx.x] += u;
        __syncthreads();
    }
    int bbase = (b == 0) ? 0 : bb[b-1];          // exclusive prefix
    int bcnt  = bb[b] - bbase;
    const int* st = staged + b * BCAP;
    int n0 = b * NPB;
    int n1 = min(n0 + NPB, N_NODES);
    int nn = n1 - n0;
    for (int t = threadIdx.x; t < NPB; t += 512) ldeg[t] = 0;
    __syncthreads();
    for (int k = threadIdx.x; k < bcnt; k += 512)
        atomicAdd(&ldeg[st[k] >> 17], 1);
    __syncthreads();
    sc[threadIdx.x] = (threadIdx.x < nn) ? ldeg[threadIdx.x] : 0;
    __syncthreads();
    for (int off = 1; off < 512; off <<= 1) {
        int u = 0;
        if (threadIdx.x >= off) u = sc[threadIdx.x - off];
        __syncthreads();
        sc[threadIdx.x] += u;
        __syncthreads();
    }
    if (threadIdx.x < nn) {
        int pre = sc[threadIdx.x] - ldeg[threadIdx.x];     // exclusive
        rowptr[n0 + threadIdx.x] = bbase + pre;
        cursor[threadIdx.x] = bbase + pre;
    }
    if (b == 0 && threadIdx.x == 0) rowptr[N_NODES] = bb[NBUCK-1];
    __syncthreads();
    for (int k = threadIdx.x; k < bcnt; k += 512) {
        int v = st[k];
        int pos = atomicAdd(&cursor[v >> 17], 1);
        csr_src[pos] = v & 0x1FFFF;
    }
}

// ---------------- gather/softmax aggregation with fused MFMA epilogue --------
// 16 lanes/node; unconditional prefetch of neighbor rows 0..23 (rows >= deg
// resolve to row 0 = L1-hit, weight 0); only deg>24 pays a serial round.
// MODE 1: o = film(relu(agg)+..., gb);  z2 = o @ Wg2 -> zout, es_o/ed_o
// MODE 2: o = relu(agg);  out = relu(o@Wc1+bc1)@Wc2+bc2 + 0.03*flagMLP
__device__ __forceinline__ float4 h4_to_f4(half4 h) {
    float4 f;
    f.x = (float)h.x; f.y = (float)h.y; f.z = (float)h.z; f.w = (float)h.w;
    return f;
}

template<int MODE>
__global__ __launch_bounds__(256) void k_agg_f(
        const int* __restrict__ rowptr, const int* __restrict__ csr_src,
        const float* __restrict__ es, const float* __restrict__ ed,
        const half_t* __restrict__ z, const float* __restrict__ bg,
        const int* __restrict__ batch, const float* __restrict__ gb,
        const half_t* __restrict__ Wp,                  // packed B fragments
        const float* __restrict__ av_s, const float* __restrict__ av_d,
        half_t* __restrict__ zout, float* __restrict__ es_o, float* __restrict__ ed_o,
        const float* __restrict__ x,
        const float* __restrict__ bc1, const float* __restrict__ Wc2,
        const float* __restrict__ bc2,
        const float* __restrict__ Wh1, const float* __restrict__ bh1,
        const float* __restrict__ Wh2, const float* __restrict__ bh2,
        float* __restrict__ out) {
    __shared__ __align__(16) half_t h_l[1024];     // 16x64 tile, XOR-swizzled
    __shared__ __align__(16) half_t zl16[1024];    // MODE1: z repack tile
    __shared__ float red[4][16][4];                // cross-wave partials
    int tidb = threadIdx.x;
    int il = tidb >> 4;          // local node 0..15
    int sl = tidb & 15;
    int m0 = blockIdx.x * 16;
    int i = m0 + il;

    // ---- hoisted epilogue parameter loads (uniform, issue first) ----
    int l    = tidb & 63;
    int wave = tidb >> 6;
    int c    = l & 15;
    int g    = l >> 4;
    const half8* wp = (const half8*)(Wp + ((size_t)tidb << 4));
    half8 Bf0 = wp[0];
    half8 Bf1 = wp[1];
    float as_w = 0.f, ad_w = 0.f, bc1w = 0.f;
    float4 w2w = {0.f, 0.f, 0.f, 0.f};
    if (MODE == 1) {
        as_w = av_s[c + 16*wave] * LOG2E;
        ad_w = av_d[c + 16*wave] * LOG2E;
    } else {
        bc1w = bc1[c + 16*wave];
        w2w  = ((const float4*)Wc2)[c + 16*wave];
    }

    int beg = rowptr[i], end = rowptr[i+1];
    int deg = end - beg;
    float edi = ed[i];

    int svA = 0, svB = 0;
    if (sl < deg)      svA = csr_src[beg + sl];
    if (16 + sl < deg) svB = csr_src[beg + 16 + sl];

    // broadcast neighbor ids, issue rows 0..15 AND 16..23 unconditionally
    // (lanes beyond deg hold sv=0 -> row 0, L1-resident; weighted by 0 below)
    const half4* z4 = (const half4*)z;
    int aP[16];
    #pragma unroll
    for (int j = 0; j < 16; j++) aP[j] = __shfl(svA, j, 16);
    half4 qP[16];
    #pragma unroll
    for (int j = 0; j < 16; j++) qP[j] = z4[aP[j]*16 + sl];
    int bP[8];
    #pragma unroll
    for (int j = 0; j < 8; j++) bP[j] = __shfl(svB, j, 16);
    half4 qB[8];
    #pragma unroll
    for (int j = 0; j < 8; j++) qB[j] = z4[bP[j]*16 + sl];
    float4 zi = h4_to_f4(z4[i*16 + sl]);
    // es gathers fly concurrently with the row loads above
    float esA = es[svA];
    float esB = es[svB];
    float e_self = es[i] + edi;
    e_self = fmaxf(e_self, 0.2f * e_self);
    float vA = esA + edi, vB = esB + edi;
    float exA = (sl < deg)      ? exp2f(fmaxf(vA, 0.2f * vA)) : 0.f;
    float exB = (16 + sl < deg) ? exp2f(fmaxf(vB, 0.2f * vB)) : 0.f;

    float s = exA + exB;
    #pragma unroll
    for (int off = 1; off < 16; off <<= 1)
        s += __shfl_xor(s, off, 16);
    float ex = exp2f(e_self);
    s += ex;

    float4 acc = {ex*zi.x, ex*zi.y, ex*zi.z, ex*zi.w};

    // FMA the 16 prefetched rows (weight 0 for j >= deg)
    #pragma unroll
    for (int j = 0; j < 16; j++) {
        float e = __shfl(exA, j, 16);
        float4 r = h4_to_f4(qP[j]);
        acc.x += e*r.x; acc.y += e*r.y;
        acc.z += e*r.z; acc.w += e*r.w;
    }

    if (deg > 16) {
        // rows 16..23: already prefetched
        #pragma unroll
        for (int j = 0; j < 8; j++) {
            float e = __shfl(exB, j, 16);
            float4 r = h4_to_f4(qB[j]);
            acc.x += e*r.x; acc.y += e*r.y;
            acc.z += e*r.z; acc.w += e*r.w;
        }
        if (deg > 24) {
            int lim = (deg < 32) ? deg : 32;
            for (int k = 24; k < lim; k++) {
                int a = __shfl(svB, k-16, 16);
                float e2 = __shfl(exB, k-16, 16);
                float4 zr = h4_to_f4(z4[a*16 + sl]);
                acc.x += e2*zr.x; acc.y += e2*zr.y; acc.z += e2*zr.z; acc.w += e2*zr.w;
            }
            for (int kk = beg + 32; kk < end; kk++) {   // rare: deg > 32
                int sv = csr_src[kk];
                float v = es[sv] + edi;
                float e2 = exp2f(fmaxf(v, 0.2f * v));
                s += e2;
                float4 zr = h4_to_f4(z4[sv*16 + sl]);
                acc.x += e2*zr.x; acc.y += e2*zr.y; acc.z += e2*zr.z; acc.w += e2*zr.w;
            }
        }
    }
    float inv = 1.f / (s + 1e-16f);
    float4 bg4 = ((const float4*)bg)[sl];
    float4 o;
    o.x = fmaxf(acc.x*inv + bg4.x, 0.f);
    o.y = fmaxf(acc.y*inv + bg4.y, 0.f);
    o.z = fmaxf(acc.z*inv + bg4.z, 0.f);
    o.w = fmaxf(acc.w*inv + bg4.w, 0.f);
    if (MODE == 1) {
        int gidx = batch[i];
        const float4* gb4 = (const float4*)gb;
        float4 ga = gb4[gidx*32 + sl];
        float4 be = gb4[gidx*32 + 16 + sl];
        o.x = o.x*(1.f+ga.x) + be.x;
        o.y = o.y*(1.f+ga.y) + be.y;
        o.z = o.z*(1.f+ga.z) + be.z;
        o.w = o.w*(1.f+ga.w) + be.w;
    }
    half4 hv;
    hv.x = (half_t)o.x; hv.y = (half_t)o.y; hv.z = (half_t)o.z; hv.w = (half_t)o.w;
    // store h-tile to LDS, XOR-swizzled so A-frag ds_read_b128 is conflict-free
    *(half4*)((char*)h_l + il*128 + ((sl*8) ^ ((il & 7) << 4))) = hv;

    __syncthreads();
    half8 A0 = *(const half8*)((const char*)h_l + c*128 + ((g*16)      ^ ((c & 7) << 4)));
    half8 A1 = *(const half8*)((const char*)h_l + c*128 + ((64 + g*16) ^ ((c & 7) << 4)));
    floatx4 D = {0.f, 0.f, 0.f, 0.f};
    D = __builtin_amdgcn_mfma_f32_16x16x32_f16(A0, Bf0, D, 0, 0, 0);
    D = __builtin_amdgcn_mfma_f32_16x16x32_f16(A1, Bf1, D, 0, 0, 0);
    if (MODE == 1) {
        #pragma unroll
        for (int r = 0; r < 4; r++) {
            float ps = D[r]*as_w, pd = D[r]*ad_w;
            #pragma unroll
            for (int off = 1; off < 16; off <<= 1) {
                ps += __shfl_xor(ps, off, 16);
                pd += __shfl_xor(pd, off, 16);
            }
            if (c == 0) {
                red[wave][g*4 + r][0] = ps;
                red[wave][g*4 + r][1] = pd;
            }
            zl16[(g*4 + r)*64 + c + 16*wave] = (half_t)D[r];
        }
        __syncthreads();
        if (tidb < 16) {
            es_o[m0 + tidb] = red[0][tidb][0] + red[1][tidb][0] + red[2][tidb][0] + red[3][tidb][0];
            ed_o[m0 + tidb] = red[0][tidb][1] + red[1][tidb][1] + red[2][tidb][1] + red[3][tidb][1];
        }
        if (tidb < 128)
            ((half8*)(zout + (size_t)m0 * 64))[tidb] = ((const half8*)zl16)[tidb];
    } else {
        #pragma unroll
        for (int r = 0; r < 4; r++) {
            float tv = fmaxf(D[r] + bc1w, 0.f);
            float px = tv*w2w.x, py = tv*w2w.y, pz = tv*w2w.z, pw = tv*w2w.w;
            #pragma unroll
            for (int off = 1; off < 16; off <<= 1) {
                px += __shfl_xor(px, off, 16);
                py += __shfl_xor(py, off, 16);
                pz += __shfl_xor(pz, off, 16);
                pw += __shfl_xor(pw, off, 16);
            }
            if (c == 0) {
                red[wave][g*4 + r][0] = px;
                red[wave][g*4 + r][1] = py;
                red[wave][g*4 + r][2] = pz;
                red[wave][g*4 + r][3] = pw;
            }
        }
        __syncthreads();
        if (tidb < 16) {
            int m = m0 + tidb;
            float p0 = red[0][tidb][0] + red[1][tidb][0] + red[2][tidb][0] + red[3][tidb][0] + bc2[0];
            float p1 = red[0][tidb][1] + red[1][tidb][1] + red[2][tidb][1] + red[3][tidb][1] + bc2[1];
            float p2 = red[0][tidb][2] + red[1][tidb][2] + red[2][tidb][2] + red[3][tidb][2] + bc2[2];
            float p3 = red[0][tidb][3] + red[1][tidb][3] + red[2][tidb][3] + red[3][tidb][3] + bc2[3];
            float f0 = x[m*8+6], f1 = x[m*8+7];
            float t8[8];
            #pragma unroll
            for (int q = 0; q < 8; q++)
                t8[q] = fmaxf(f0*Wh1[q] + f1*Wh1[8+q] + bh1[q], 0.f);
            float fl[4];
            #pragma unroll
            for (int q = 0; q < 4; q++) {
                float a = bh2[q];
                #pragma unroll
                for (int rr = 0; rr < 8; rr++) a += t8[rr]*Wh2[rr*4+q];
                fl[q] = a;
            }
            float4 ov;
            ov.x = p0 + 0.03f*fl[0];
            ov.y = p1 + 0.03f*fl[1];
            ov.z = p2 + 0.03f*fl[2];
            ov.w = p3 + 0.03f*fl[3];
            ((float4*)out)[m] = ov;
        }
    }
}

extern "C" void kernel_launch(void* const* d_in, const int* in_sizes, int n_in,
                              void* d_out, int out_size, void* d_ws, size_t ws_size,
                              hipStream_t stream) {
    const float* x       = (const float*)d_in[0];
    const int*   ei      = (const int*)  d_in[1];
    const int*   batch   = (const int*)  d_in[2];
    const float* climber = (const float*)d_in[3];
    const float* W_in    = (const float*)d_in[4];
    const float* b_in    = (const float*)d_in[5];
    const float* ln_g    = (const float*)d_in[6];
    const float* ln_b    = (const float*)d_in[7];
    const float* W_c     = (const float*)d_in[8];
    const float* b_c     = (const float*)d_in[9];
    const float* Wf1     = (const float*)d_in[10];
    const float* bf1     = (const float*)d_in[11];
    const float* Wf2     = (const float*)d_in[12];
    const float* bf2     = (const float*)d_in[13];
    const float* Wg1     = (const float*)d_in[14];
    const float* as1     = (const float*)d_in[15];
    const float* ad1     = (const float*)d_in[16];
    const float* bg1     = (const float*)d_in[17];
    const float* Wg2     = (const float*)d_in[18];
    const float* as2     = (const float*)d_in[19];
    const float* ad2     = (const float*)d_in[20];
    const float* bg2     = (const float*)d_in[21];
    const float* Wc1     = (const float*)d_in[22];
    const float* bc1     = (const float*)d_in[23];
    const float* Wc2     = (const float*)d_in[24];
    const float* bc2     = (const float*)d_in[25];
    const float* Wh1     = (const float*)d_in[26];
    const float* bh1     = (const float*)d_in[27];
    const float* Wh2     = (const float*)d_in[28];
    const float* bh2     = (const float*)d_in[29];
    float* out = (float*)d_out;
    float* ws  = (float*)d_ws;

    // workspace carve (float units; all vector-accessed regions 16B-aligned)
    float*  gb1         = ws;                        // 128,000
    float*  gb2         = gb1 + 128000;              // 128,000
    half_t* Wp1         = (half_t*)(gb2 + 128000);   // 4096 halfs (packed Wg2)
    half_t* Wp2         = Wp1 + 4096;                // 4096 halfs (packed Wc1)
    half_t* zA          = Wp2 + 4096;                // 6.4M halfs (layer-1 z)
    half_t* zB          = zA + 6400000;              // 6.4M halfs (layer-2 z)
    float*  es1         = (float*)(zB + 6400000);    // 100,000
    float*  ed1         = es1 + N_NODES;             // 100,000
    float*  es2         = ed1 + N_NODES;             // 100,000
    float*  ed2         = es2 + N_NODES;             // 100,000
    int*    rowptr      = (int*)(ed2 + N_NODES);     // 100,001
    int*    csr_src     = rowptr + N_NODES + 1;      // 1,200,000
    int*    bucket_fill = csr_src + N_EDGES;         // 256 (zeroed by k_film)
    int*    staged      = bucket_fill + NBUCK;       // 256*8192

    // FiLM coeffs + W-frag packing + bucket_fill zero
    k_film<<<127, 1024, 0, stream>>>(climber, ln_g, ln_b, W_c, b_c,
                                     Wf1, bf1, Wf2, bf2, Wg2, Wc1,
                                     gb1, gb2, Wp1, Wp2, bucket_fill);

    // edge binning (blocks 0..585) || layer-1 MFMA z1 (blocks 586..1097)
    k_pre2<<<S3_BLOCKS + Z1_BLOCKS, 512, 0, stream>>>(ei, bucket_fill, staged,
                                                      x, batch, W_in, b_in, gb1, Wg1,
                                                      as1, ad1, zA, es1, ed1);

    // CSR compaction
    k_bcsr<<<NBUCK, 512, 0, stream>>>(staged, bucket_fill, rowptr, csr_src);

    // layer-1 aggregation + FiLM2 + fused z2 = h1@Wg2 (+ es2/ed2)
    k_agg_f<1><<<AGG_BLOCKS, 256, 0, stream>>>(rowptr, csr_src, es1, ed1, zA, bg1,
                                               batch, gb2, Wp1, as2, ad2,
                                               zB, es2, ed2,
                                               nullptr, nullptr, nullptr, nullptr,
                                               nullptr, nullptr, nullptr, nullptr,
                                               nullptr);

    // layer-2 aggregation + fused classifier/flag head
    k_agg_f<2><<<AGG_BLOCKS, 256, 0, stream>>>(rowptr, csr_src, es2, ed2, zB, bg2,
                                               batch, nullptr, Wp2, nullptr, nullptr,
                                               nullptr, nullptr, nullptr,
                                               x, bc1, Wc2, bc2, Wh1, bh1, Wh2, bh2,
                                               out);
}

// Round 8
// 232.525 us; speedup vs baseline: 1.0253x; 1.0253x over previous
//
#include <hip/hip_runtime.h>
#include <math.h>

#define N_NODES 100000
#define N_EDGES 1200000
#define N_GRAPHS 1000
#define HID 64
#define NBUCK 256
#define NPB   391
#define BCAP  8192           // fixed staging capacity per bucket (~50 sigma)
#define EDGE_CHUNK 4096
#define S3_BLOCKS ((N_EDGES + EDGE_CHUNK - 1) / EDGE_CHUNK)   // 293
#define Z1_BLOCKS 256
#define LOG2E 1.4426950408889634f
#define N_TILES (N_NODES / 16)      // 6250, exact
#define AGG_BLOCKS (N_NODES / 16)   // 6250, exact

typedef _Float16 half_t;
typedef __attribute__((ext_vector_type(4))) _Float16 half4;
typedef __attribute__((ext_vector_type(8))) _Float16 half8;
typedef __attribute__((ext_vector_type(4))) float floatx4;

// ---------------- k_film: climber FiLM + W-pack + bucket_fill zero -----------
// blocks [0,125): climber LN + FiLM coeffs, 8 graphs per block
// blocks 125,126: pack Wg2 / Wc1 into per-lane MFMA fragment order:
//   Wp[((w*64+l)*2+ko)*8+j] = (half)W[(ko*32+(l>>4)*8+j)*64 + (l&15) + 16*w]
// block 0 additionally zeroes bucket_fill.
__global__ __launch_bounds__(1024) void k_film(
        const float* __restrict__ climber,
        const float* __restrict__ ln_g, const float* __restrict__ ln_b,
        const float* __restrict__ W_c, const float* __restrict__ b_c,
        const float* __restrict__ Wf1, const float* __restrict__ bf1,
        const float* __restrict__ Wf2, const float* __restrict__ bf2,
        const float* __restrict__ Wg2, const float* __restrict__ Wc1,
        float* __restrict__ gb1, float* __restrict__ gb2,
        half_t* __restrict__ Wp1, half_t* __restrict__ Wp2,
        int* __restrict__ bucket_fill) {
    int bid = blockIdx.x;
    if (bid == 0 && threadIdx.x < NBUCK) bucket_fill[threadIdx.x] = 0;
    if (bid >= 125) {
        const float* Wsrc = (bid == 125) ? Wg2 : Wc1;
        half_t*      Wdst = (bid == 125) ? Wp1 : Wp2;
        for (int idx = threadIdx.x; idx < 4096; idx += 1024) {
            int jj = idx & 7;
            int ko = (idx >> 3) & 1;
            int l  = (idx >> 4) & 63;
            int w  = idx >> 10;
            int c  = l & 15;
            int gg = l >> 4;
            Wdst[idx] = (half_t)Wsrc[(ko*32 + gg*8 + jj)*64 + c + 16*w];
        }
        return;
    }
    __shared__ float cl[8][64];
    int sub = threadIdx.x >> 7;         // graph-subgroup 0..7
    int j   = threadIdx.x & 127;
    int g   = bid * 8 + sub;
    if (j < 64) {
        float v[6];
        float mu = 0.f;
        #pragma unroll
        for (int k = 0; k < 6; k++) { v[k] = climber[g*6+k]; mu += v[k]; }
        mu *= (1.f/6.f);
        float var = 0.f;
        #pragma unroll
        for (int k = 0; k < 6; k++) { float d = v[k]-mu; var += d*d; }
        var *= (1.f/6.f);
        float rs = rsqrtf(var + 1e-5f);
        float acc = b_c[j];
        #pragma unroll
        for (int k = 0; k < 6; k++) {
            float cn = (v[k]-mu)*rs*ln_g[k] + ln_b[k];
            acc += cn * W_c[k*64+j];
        }
        cl[sub][j] = fmaxf(acc, 0.f);
    }
    __syncthreads();
    float a1 = bf1[j], a2 = bf2[j];
    #pragma unroll 8
    for (int k = 0; k < 64; k++) {
        float ck = cl[sub][k];
        a1 += ck * Wf1[k*128+j];
        a2 += ck * Wf2[k*128+j];
    }
    gb1[g*128+j] = a1;
    gb2[g*128+j] = a2;
}

// ---------------- k_pre2: edge binning (blocks < S3)  ||  layer-1 MFMA -------
// bin: single edge-list read; src/dst/bucket retained in registers.
// staged entry: (local_dst << 17) | src   (src < 2^17, local_dst < 512)
// z1: h1 = film1(x@W_in+b_in); z = h1@Wg1 (row-major); es/ed
__global__ __launch_bounds__(1024) void k_pre2(
        const int* __restrict__ ei, int* __restrict__ bucket_fill,
        int* __restrict__ staged,
        const float* __restrict__ x, const int* __restrict__ batch,
        const float* __restrict__ W_in, const float* __restrict__ b_in,
        const float* __restrict__ gb1, const float* __restrict__ W,
        const float* __restrict__ a_src, const float* __restrict__ a_dst,
        half_t* __restrict__ z, float* __restrict__ es, float* __restrict__ ed) {
    if (blockIdx.x < S3_BLOCKS) {
        // -------- bin role --------
        __shared__ int hist[NBUCK];
        __shared__ int cursor[NBUCK];
        for (int t = threadIdx.x; t < NBUCK; t += 1024) hist[t] = 0;
        __syncthreads();
        int e0 = blockIdx.x * EDGE_CHUNK;
        int n  = min(EDGE_CHUNK, N_EDGES - e0);
        int srcs[4], ldsts[4], bks[4];
        #pragma unroll
        for (int j = 0; j < 4; j++) {
            int idx = threadIdx.x + j*1024;
            bks[j] = -1;
            if (idx < n) {
                int e = e0 + idx;
                srcs[j] = ei[e];
                int dst = ei[N_EDGES + e];
                int b = dst / NPB;
                bks[j] = b;
                ldsts[j] = dst - b * NPB;
                atomicAdd(&hist[b], 1);
            }
        }
        __syncthreads();
        if (threadIdx.x < NBUCK) {
            int hv = hist[threadIdx.x];
            int start = threadIdx.x * BCAP;
            if (hv) start += atomicAdd(&bucket_fill[threadIdx.x], hv);
            cursor[threadIdx.x] = start;
        }
        __syncthreads();
        #pragma unroll
        for (int j = 0; j < 4; j++) {
            if (bks[j] >= 0) {
                int pos = atomicAdd(&cursor[bks[j]], 1);
                staged[pos] = (ldsts[j] << 17) | srcs[j];
            }
        }
        return;
    }
    // -------- z1 role --------
    __shared__ float Wi[384];                // W_in row-major 6x64
    __shared__ float bi[64];
    __shared__ __align__(16) half_t zl[16][1024];
    for (int idx = threadIdx.x; idx < 384; idx += 1024) Wi[idx] = W_in[idx];
    if (threadIdx.x < 64) bi[threadIdx.x] = b_in[threadIdx.x];
    int wave = threadIdx.x >> 6;
    int l    = threadIdx.x & 63;
    int c    = l & 15;
    int g    = l >> 4;
    half8 Bf[2][4];
    #pragma unroll
    for (int ko = 0; ko < 2; ko++) {
        #pragma unroll
        for (int nt = 0; nt < 4; nt++) {
            half8 bvec;
            #pragma unroll
            for (int j = 0; j < 8; j++)
                bvec[j] = (half_t)W[(ko*32 + g*8 + j)*64 + c + 16*nt];
            Bf[ko][nt] = bvec;
        }
    }
    float as4[4], ad4[4];
    #pragma unroll
    for (int nt = 0; nt < 4; nt++) {
        as4[nt] = a_src[c + 16*nt] * LOG2E;
        ad4[nt] = a_dst[c + 16*nt] * LOG2E;
    }
    __syncthreads();
    int nWaves = Z1_BLOCKS * 16;
    int wid = (blockIdx.x - S3_BLOCKS) * 16 + wave;
    half_t* zw = zl[wave];
    const float4* x4p = (const float4*)x;
    for (int t = wid; t < N_TILES; t += nWaves) {
        int m0 = t * 16;
        int i = m0 + c;
        float4 xa = x4p[i*2];
        float4 xb = x4p[i*2 + 1];
        float xv[6] = {xa.x, xa.y, xa.z, xa.w, xb.x, xb.y};
        int bg_ = batch[i];
        half8 A[2];
        #pragma unroll
        for (int s = 0; s < 2; s++) {
            int bk = s*32 + g*8;
            float acc[8];
            #pragma unroll
            for (int j = 0; j < 8; j++) acc[j] = bi[bk + j];
            #pragma unroll
            for (int kk = 0; kk < 6; kk++) {
                float xk = xv[kk];
                float4 w0 = *(const float4*)&Wi[kk*64 + bk];
                float4 w1 = *(const float4*)&Wi[kk*64 + bk + 4];
                acc[0] += xk*w0.x; acc[1] += xk*w0.y;
                acc[2] += xk*w0.z; acc[3] += xk*w0.w;
                acc[4] += xk*w1.x; acc[5] += xk*w1.y;
                acc[6] += xk*w1.z; acc[7] += xk*w1.w;
            }
            const float4* gbv = (const float4*)(gb1 + bg_*128);
            float4 ga0 = gbv[bk/4],      ga1 = gbv[bk/4 + 1];
            float4 be0 = gbv[16 + bk/4], be1 = gbv[16 + bk/4 + 1];
            half8 hv;
            hv[0] = (half_t)(acc[0]*(1.f+ga0.x) + be0.x);
            hv[1] = (half_t)(acc[1]*(1.f+ga0.y) + be0.y);
            hv[2] = (half_t)(acc[2]*(1.f+ga0.z) + be0.z);
            hv[3] = (half_t)(acc[3]*(1.f+ga0.w) + be0.w);
            hv[4] = (half_t)(acc[4]*(1.f+ga1.x) + be1.x);
            hv[5] = (half_t)(acc[5]*(1.f+ga1.y) + be1.y);
            hv[6] = (half_t)(acc[6]*(1.f+ga1.z) + be1.z);
            hv[7] = (half_t)(acc[7]*(1.f+ga1.w) + be1.w);
            A[s] = hv;
        }
        floatx4 D[4];
        #pragma unroll
        for (int nt = 0; nt < 4; nt++) {
            floatx4 acc = {0.f, 0.f, 0.f, 0.f};
            acc = __builtin_amdgcn_mfma_f32_16x16x32_f16(A[0], Bf[0][nt], acc, 0, 0, 0);
            acc = __builtin_amdgcn_mfma_f32_16x16x32_f16(A[1], Bf[1][nt], acc, 0, 0, 0);
            D[nt] = acc;
        }
        #pragma unroll
        for (int r = 0; r < 4; r++) {
            float ps = D[0][r]*as4[0] + D[1][r]*as4[1] + D[2][r]*as4[2] + D[3][r]*as4[3];
            float pd = D[0][r]*ad4[0] + D[1][r]*ad4[1] + D[2][r]*ad4[2] + D[3][r]*ad4[3];
            #pragma unroll
            for (int off = 1; off < 16; off <<= 1) {
                ps += __shfl_xor(ps, off, 16);
                pd += __shfl_xor(pd, off, 16);
            }
            if (c == 0) {
                es[m0 + g*4 + r] = ps;
                ed[m0 + g*4 + r] = pd;
            }
        }
        #pragma unroll
        for (int nt = 0; nt < 4; nt++) {
            #pragma unroll
            for (int r = 0; r < 4; r++)
                zw[(g*4 + r)*64 + c + 16*nt] = (half_t)D[nt][r];
        }
        __asm__ __volatile__("s_waitcnt lgkmcnt(0)" ::: "memory");
        const half8* zr = (const half8*)zw;
        half8 v0 = zr[l*2];
        half8 v1 = zr[l*2 + 1];
        half8* zo = (half8*)(z + (size_t)m0 * 64);
        zo[l*2]     = v0;
        zo[l*2 + 1] = v1;
        __asm__ __volatile__("s_waitcnt lgkmcnt(0)" ::: "memory");
    }
}

// ---------------- k_bcsr: compact staged -> csr_src + rowptr (512 threads) ---
__global__ __launch_bounds__(512) void k_bcsr(
        const int* __restrict__ staged, const int* __restrict__ bucket_fill,
        int* __restrict__ rowptr, int* __restrict__ csr_src) {
    __shared__ int bb[NBUCK];       // inclusive scan of bucket_fill
    __shared__ int ldeg[NPB];
    __shared__ int sc[512];
    __shared__ int cursor[NPB];
    int b = blockIdx.x;
    if (threadIdx.x < NBUCK) bb[threadIdx.x] = bucket_fill[threadIdx.x];
    __syncthreads();
    for (int off = 1; off < NBUCK; off <<= 1) {
        int u = 0;
        if (threadIdx.x < NBUCK && threadIdx.x >= off) u = bb[threadIdx.x - off];
        __syncthreads();
        if (threadIdx.x < NBUCK) bb[threadIdx.x] += u;
        __syncthreads();
    }
    int bbase = (b == 0) ? 0 : bb[b-1];          // exclusive prefix
    int bcnt  = bb[b] - bbase;
    const int* st = staged + b * BCAP;
    int n0 = b * NPB;
    int n1 = min(n0 + NPB, N_NODES);
    int nn = n1 - n0;
    for (int t = threadIdx.x; t < NPB; t += 512) ldeg[t] = 0;
    __syncthreads();
    for (int k = threadIdx.x; k < bcnt; k += 512)
        atomicAdd(&ldeg[st[k] >> 17], 1);
    __syncthreads();
    sc[threadIdx.x] = (threadIdx.x < nn) ? ldeg[threadIdx.x] : 0;
    __syncthreads();
    for (int off = 1; off < 512; off <<= 1) {
        int u = 0;
        if (threadIdx.x >= off) u = sc[threadIdx.x - off];
        __syncthreads();
        sc[threadIdx.x] += u;
        __syncthreads();
    }
    if (threadIdx.x < nn) {
        int pre = sc[threadIdx.x] - ldeg[threadIdx.x];     // exclusive
        rowptr[n0 + threadIdx.x] = bbase + pre;
        cursor[threadIdx.x] = bbase + pre;
    }
    if (b == 0 && threadIdx.x == 0) rowptr[N_NODES] = bb[NBUCK-1];
    __syncthreads();
    for (int k = threadIdx.x; k < bcnt; k += 512) {
        int v = st[k];
        int pos = atomicAdd(&cursor[v >> 17], 1);
        csr_src[pos] = v & 0x1FFFF;
    }
}

// ---------------- gather/softmax aggregation with fused MFMA epilogue --------
// (round-2/round-5 verified structure: 16 lanes/node, 16-row prefetch)
// MODE 1: o = film(relu(agg)+..., gb);  z2 = o @ Wg2 -> zout, es_o/ed_o
// MODE 2: o = relu(agg);  out = relu(o@Wc1+bc1)@Wc2+bc2 + 0.03*flagMLP
__device__ __forceinline__ float4 h4_to_f4(half4 h) {
    float4 f;
    f.x = (float)h.x; f.y = (float)h.y; f.z = (float)h.z; f.w = (float)h.w;
    return f;
}

template<int MODE>
__global__ __launch_bounds__(256) void k_agg_f(
        const int* __restrict__ rowptr, const int* __restrict__ csr_src,
        const float* __restrict__ es, const float* __restrict__ ed,
        const half_t* __restrict__ z, const float* __restrict__ bg,
        const int* __restrict__ batch, const float* __restrict__ gb,
        const half_t* __restrict__ Wp,                  // packed B fragments
        const float* __restrict__ av_s, const float* __restrict__ av_d,
        half_t* __restrict__ zout, float* __restrict__ es_o, float* __restrict__ ed_o,
        const float* __restrict__ x,
        const float* __restrict__ bc1, const float* __restrict__ Wc2,
        const float* __restrict__ bc2,
        const float* __restrict__ Wh1, const float* __restrict__ bh1,
        const float* __restrict__ Wh2, const float* __restrict__ bh2,
        float* __restrict__ out) {
    __shared__ __align__(16) half_t h_l[1024];     // 16x64 tile, XOR-swizzled
    __shared__ __align__(16) half_t zl16[1024];    // MODE1: z repack tile
    __shared__ float red[4][16][4];                // cross-wave partials
    int tidb = threadIdx.x;
    int il = tidb >> 4;          // local node 0..15
    int sl = tidb & 15;
    int m0 = blockIdx.x * 16;
    int i = m0 + il;

    // ---- hoisted epilogue parameter loads (uniform, issue first) ----
    int l    = tidb & 63;
    int wave = tidb >> 6;
    int c    = l & 15;
    int g    = l >> 4;
    const half8* wp = (const half8*)(Wp + ((size_t)tidb << 4));
    half8 Bf0 = wp[0];
    half8 Bf1 = wp[1];
    float as_w = 0.f, ad_w = 0.f, bc1w = 0.f;
    float4 w2w = {0.f, 0.f, 0.f, 0.f};
    if (MODE == 1) {
        as_w = av_s[c + 16*wave] * LOG2E;
        ad_w = av_d[c + 16*wave] * LOG2E;
    } else {
        bc1w = bc1[c + 16*wave];
        w2w  = ((const float4*)Wc2)[c + 16*wave];
    }

    int beg = rowptr[i], end = rowptr[i+1];
    int deg = end - beg;
    float edi = ed[i];

    int svA = 0, svB = 0;
    if (sl < deg)      svA = csr_src[beg + sl];
    if (16 + sl < deg) svB = csr_src[beg + 16 + sl];

    // broadcast all 16 svA neighbor ids, issue all row loads unconditionally
    // (lanes beyond deg hold svA=0 -> row 0, L1-resident; weighted by 0 below)
    const half4* z4 = (const half4*)z;
    int aP[16];
    #pragma unroll
    for (int j = 0; j < 16; j++) aP[j] = __shfl(svA, j, 16);
    half4 qP[16];
    #pragma unroll
    for (int j = 0; j < 16; j++) qP[j] = z4[aP[j]*16 + sl];
    float4 zi = h4_to_f4(z4[i*16 + sl]);
    // es gathers fly concurrently with the row loads above
    float esA = es[svA];
    float esB = es[svB];
    float e_self = es[i] + edi;
    e_self = fmaxf(e_self, 0.2f * e_self);
    float vA = esA + edi, vB = esB + edi;
    float exA = (sl < deg)      ? exp2f(fmaxf(vA, 0.2f * vA)) : 0.f;
    float exB = (16 + sl < deg) ? exp2f(fmaxf(vB, 0.2f * vB)) : 0.f;

    float s = exA + exB;
    #pragma unroll
    for (int off = 1; off < 16; off <<= 1)
        s += __shfl_xor(s, off, 16);
    float ex = exp2f(e_self);
    s += ex;

    float4 acc = {ex*zi.x, ex*zi.y, ex*zi.z, ex*zi.w};

    // FMA the 16 prefetched rows (weight 0 for j >= deg)
    #pragma unroll
    for (int j = 0; j < 16; j++) {
        float e = __shfl(exA, j, 16);
        float4 r = h4_to_f4(qP[j]);
        acc.x += e*r.x; acc.y += e*r.y;
        acc.z += e*r.z; acc.w += e*r.w;
    }

    if (deg > 16) {
        int lim = (deg < 32) ? deg : 32;
        int k = 16;
        for (; k + 8 <= lim; k += 8) {
            int a[8]; float e[8];
            #pragma unroll
            for (int j = 0; j < 8; j++) {
                a[j] = __shfl(svB, k-16+j, 16);
                e[j] = __shfl(exB, k-16+j, 16);
            }
            half4 q[8];
            #pragma unroll
            for (int j = 0; j < 8; j++) q[j] = z4[a[j]*16 + sl];
            #pragma unroll
            for (int j = 0; j < 8; j++) {
                float4 r = h4_to_f4(q[j]);
                acc.x += e[j]*r.x; acc.y += e[j]*r.y;
                acc.z += e[j]*r.z; acc.w += e[j]*r.w;
            }
        }
        for (; k + 4 <= lim; k += 4) {
            int a[4]; float e[4];
            #pragma unroll
            for (int j = 0; j < 4; j++) {
                a[j] = __shfl(svB, k-16+j, 16);
                e[j] = __shfl(exB, k-16+j, 16);
            }
            half4 q[4];
            #pragma unroll
            for (int j = 0; j < 4; j++) q[j] = z4[a[j]*16 + sl];
            #pragma unroll
            for (int j = 0; j < 4; j++) {
                float4 r = h4_to_f4(q[j]);
                acc.x += e[j]*r.x; acc.y += e[j]*r.y;
                acc.z += e[j]*r.z; acc.w += e[j]*r.w;
            }
        }
        for (; k < lim; k++) {
            int a = __shfl(svB, k-16, 16);
            float e2 = __shfl(exB, k-16, 16);
            float4 zr = h4_to_f4(z4[a*16 + sl]);
            acc.x += e2*zr.x; acc.y += e2*zr.y; acc.z += e2*zr.z; acc.w += e2*zr.w;
        }
        for (int kk = beg + 32; kk < end; kk++) {   // rare: deg > 32
            int sv = csr_src[kk];
            float v = es[sv] + edi;
            float e2 = exp2f(fmaxf(v, 0.2f * v));
            s += e2;
            float4 zr = h4_to_f4(z4[sv*16 + sl]);
            acc.x += e2*zr.x; acc.y += e2*zr.y; acc.z += e2*zr.z; acc.w += e2*zr.w;
        }
    }
    float inv = 1.f / (s + 1e-16f);
    float4 bg4 = ((const float4*)bg)[sl];
    float4 o;
    o.x = fmaxf(acc.x*inv + bg4.x, 0.f);
    o.y = fmaxf(acc.y*inv + bg4.y, 0.f);
    o.z = fmaxf(acc.z*inv + bg4.z, 0.f);
    o.w = fmaxf(acc.w*inv + bg4.w, 0.f);
    if (MODE == 1) {
        int gidx = batch[i];
        const float4* gb4 = (const float4*)gb;
        float4 ga = gb4[gidx*32 + sl];
        float4 be = gb4[gidx*32 + 16 + sl];
        o.x = o.x*(1.f+ga.x) + be.x;
        o.y = o.y*(1.f+ga.y) + be.y;
        o.z = o.z*(1.f+ga.z) + be.z;
        o.w = o.w*(1.f+ga.w) + be.w;
    }
    half4 hv;
    hv.x = (half_t)o.x; hv.y = (half_t)o.y; hv.z = (half_t)o.z; hv.w = (half_t)o.w;
    // store h-tile to LDS, XOR-swizzled so A-frag ds_read_b128 is conflict-free
    *(half4*)((char*)h_l + il*128 + ((sl*8) ^ ((il & 7) << 4))) = hv;

    __syncthreads();
    half8 A0 = *(const half8*)((const char*)h_l + c*128 + ((g*16)      ^ ((c & 7) << 4)));
    half8 A1 = *(const half8*)((const char*)h_l + c*128 + ((64 + g*16) ^ ((c & 7) << 4)));
    floatx4 D = {0.f, 0.f, 0.f, 0.f};
    D = __builtin_amdgcn_mfma_f32_16x16x32_f16(A0, Bf0, D, 0, 0, 0);
    D = __builtin_amdgcn_mfma_f32_16x16x32_f16(A1, Bf1, D, 0, 0, 0);
    if (MODE == 1) {
        #pragma unroll
        for (int r = 0; r < 4; r++) {
            float ps = D[r]*as_w, pd = D[r]*ad_w;
            #pragma unroll
            for (int off = 1; off < 16; off <<= 1) {
                ps += __shfl_xor(ps, off, 16);
                pd += __shfl_xor(pd, off, 16);
            }
            if (c == 0) {
                red[wave][g*4 + r][0] = ps;
                red[wave][g*4 + r][1] = pd;
            }
            zl16[(g*4 + r)*64 + c + 16*wave] = (half_t)D[r];
        }
        __syncthreads();
        if (tidb < 16) {
            es_o[m0 + tidb] = red[0][tidb][0] + red[1][tidb][0] + red[2][tidb][0] + red[3][tidb][0];
            ed_o[m0 + tidb] = red[0][tidb][1] + red[1][tidb][1] + red[2][tidb][1] + red[3][tidb][1];
        }
        if (tidb < 128)
            ((half8*)(zout + (size_t)m0 * 64))[tidb] = ((const half8*)zl16)[tidb];
    } else {
        #pragma unroll
        for (int r = 0; r < 4; r++) {
            float tv = fmaxf(D[r] + bc1w, 0.f);
            float px = tv*w2w.x, py = tv*w2w.y, pz = tv*w2w.z, pw = tv*w2w.w;
            #pragma unroll
            for (int off = 1; off < 16; off <<= 1) {
                px += __shfl_xor(px, off, 16);
                py += __shfl_xor(py, off, 16);
                pz += __shfl_xor(pz, off, 16);
                pw += __shfl_xor(pw, off, 16);
            }
            if (c == 0) {
                red[wave][g*4 + r][0] = px;
                red[wave][g*4 + r][1] = py;
                red[wave][g*4 + r][2] = pz;
                red[wave][g*4 + r][3] = pw;
            }
        }
        __syncthreads();
        if (tidb < 16) {
            int m = m0 + tidb;
            float p0 = red[0][tidb][0] + red[1][tidb][0] + red[2][tidb][0] + red[3][tidb][0] + bc2[0];
            float p1 = red[0][tidb][1] + red[1][tidb][1] + red[2][tidb][1] + red[3][tidb][1] + bc2[1];
            float p2 = red[0][tidb][2] + red[1][tidb][2] + red[2][tidb][2] + red[3][tidb][2] + bc2[2];
            float p3 = red[0][tidb][3] + red[1][tidb][3] + red[2][tidb][3] + red[3][tidb][3] + bc2[3];
            float f0 = x[m*8+6], f1 = x[m*8+7];
            float t8[8];
            #pragma unroll
            for (int q = 0; q < 8; q++)
                t8[q] = fmaxf(f0*Wh1[q] + f1*Wh1[8+q] + bh1[q], 0.f);
            float fl[4];
            #pragma unroll
            for (int q = 0; q < 4; q++) {
                float a = bh2[q];
                #pragma unroll
                for (int rr = 0; rr < 8; rr++) a += t8[rr]*Wh2[rr*4+q];
                fl[q] = a;
            }
            float4 ov;
            ov.x = p0 + 0.03f*fl[0];
            ov.y = p1 + 0.03f*fl[1];
            ov.z = p2 + 0.03f*fl[2];
            ov.w = p3 + 0.03f*fl[3];
            ((float4*)out)[m] = ov;
        }
    }
}

extern "C" void kernel_launch(void* const* d_in, const int* in_sizes, int n_in,
                              void* d_out, int out_size, void* d_ws, size_t ws_size,
                              hipStream_t stream) {
    const float* x       = (const float*)d_in[0];
    const int*   ei      = (const int*)  d_in[1];
    const int*   batch   = (const int*)  d_in[2];
    const float* climber = (const float*)d_in[3];
    const float* W_in    = (const float*)d_in[4];
    const float* b_in    = (const float*)d_in[5];
    const float* ln_g    = (const float*)d_in[6];
    const float* ln_b    = (const float*)d_in[7];
    const float* W_c     = (const float*)d_in[8];
    const float* b_c     = (const float*)d_in[9];
    const float* Wf1     = (const float*)d_in[10];
    const float* bf1     = (const float*)d_in[11];
    const float* Wf2     = (const float*)d_in[12];
    const float* bf2     = (const float*)d_in[13];
    const float* Wg1     = (const float*)d_in[14];
    const float* as1     = (const float*)d_in[15];
    const float* ad1     = (const float*)d_in[16];
    const float* bg1     = (const float*)d_in[17];
    const float* Wg2     = (const float*)d_in[18];
    const float* as2     = (const float*)d_in[19];
    const float* ad2     = (const float*)d_in[20];
    const float* bg2     = (const float*)d_in[21];
    const float* Wc1     = (const float*)d_in[22];
    const float* bc1     = (const float*)d_in[23];
    const float* Wc2     = (const float*)d_in[24];
    const float* bc2     = (const float*)d_in[25];
    const float* Wh1     = (const float*)d_in[26];
    const float* bh1     = (const float*)d_in[27];
    const float* Wh2     = (const float*)d_in[28];
    const float* bh2     = (const float*)d_in[29];
    float* out = (float*)d_out;
    float* ws  = (float*)d_ws;

    // workspace carve (float units; all vector-accessed regions 16B-aligned)
    float*  gb1         = ws;                        // 128,000
    float*  gb2         = gb1 + 128000;              // 128,000
    half_t* Wp1         = (half_t*)(gb2 + 128000);   // 4096 halfs (packed Wg2)
    half_t* Wp2         = Wp1 + 4096;                // 4096 halfs (packed Wc1)
    half_t* zA          = Wp2 + 4096;                // 6.4M halfs (layer-1 z)
    half_t* zB          = zA + 6400000;              // 6.4M halfs (layer-2 z)
    float*  es1         = (float*)(zB + 6400000);    // 100,000
    float*  ed1         = es1 + N_NODES;             // 100,000
    float*  es2         = ed1 + N_NODES;             // 100,000
    float*  ed2         = es2 + N_NODES;             // 100,000
    int*    rowptr      = (int*)(ed2 + N_NODES);     // 100,001
    int*    csr_src     = rowptr + N_NODES + 1;      // 1,200,000
    int*    bucket_fill = csr_src + N_EDGES;         // 256 (zeroed by k_film)
    int*    staged      = bucket_fill + NBUCK;       // 256*8192

    // FiLM coeffs + W-frag packing + bucket_fill zero
    k_film<<<127, 1024, 0, stream>>>(climber, ln_g, ln_b, W_c, b_c,
                                     Wf1, bf1, Wf2, bf2, Wg2, Wc1,
                                     gb1, gb2, Wp1, Wp2, bucket_fill);

    // edge binning (blocks 0..292) || layer-1 MFMA z1 (blocks 293..548)
    k_pre2<<<S3_BLOCKS + Z1_BLOCKS, 1024, 0, stream>>>(ei, bucket_fill, staged,
                                                       x, batch, W_in, b_in, gb1, Wg1,
                                                       as1, ad1, zA, es1, ed1);

    // CSR compaction
    k_bcsr<<<NBUCK, 512, 0, stream>>>(staged, bucket_fill, rowptr, csr_src);

    // layer-1 aggregation + FiLM2 + fused z2 = h1@Wg2 (+ es2/ed2)
    k_agg_f<1><<<AGG_BLOCKS, 256, 0, stream>>>(rowptr, csr_src, es1, ed1, zA, bg1,
                                               batch, gb2, Wp1, as2, ad2,
                                               zB, es2, ed2,
                                               nullptr, nullptr, nullptr, nullptr,
                                               nullptr, nullptr, nullptr, nullptr,
                                               nullptr);

    // layer-2 aggregation + fused classifier/flag head
    k_agg_f<2><<<AGG_BLOCKS, 256, 0, stream>>>(rowptr, csr_src, es2, ed2, zB, bg2,
                                               batch, nullptr, Wp2, nullptr, nullptr,
                                               nullptr, nullptr, nullptr,
                                               x, bc1, Wc2, bc2, Wh1, bh1, Wh2, bh2,
                                               out);
}